// Round 1
// baseline (63103.021 us; speedup 1.0000x reference)
//
#include <hip/hip_runtime.h>
#include <math.h>

#define T_STEPS 2048
#define BATCH   32
#define IN_DIM  512
#define H_DIM   512
#define G4      (4 * H_DIM)   // 2048 gate columns
// weights: [IN_DIM + H_DIM, 4*H_DIM] row-major. rows 0..511 multiply x, rows 512..1023 multiply h.
// gate order: f = cols[0:512), i = [512:1024), g = [1024:1536), o = [1536:2048)

// ---------------------------------------------------------------------------
// Phase 1: pre[t*B+b][col] = sum_k x[t*B+b][k] * W[k][col] + bias[col]
// M = 65536, K = 512, N = 2048. BM=64, BN=64, BK=16, 256 threads, 4x4 microtile.
// ---------------------------------------------------------------------------
__global__ __launch_bounds__(256) void xw_gemm(const float* __restrict__ A,
                                               const float* __restrict__ W,
                                               const float* __restrict__ bias,
                                               float* __restrict__ C) {
    __shared__ float As[16][64];
    __shared__ float Bs[16][64];
    const int bn = blockIdx.x;   // 0..31  (N/64)
    const int bm = blockIdx.y;   // 0..1023 (M/64)
    const int tid = threadIdx.x;
    const int tm = tid >> 4;     // 0..15
    const int tn = tid & 15;     // 0..15
    const int m0 = bm * 64, n0 = bn * 64;

    float acc[4][4] = {};

    for (int k0 = 0; k0 < IN_DIM; k0 += 16) {
        // stage A tile: 64 rows x 16 k
        {
            const int r  = tid >> 2;          // 0..63
            const int kk = (tid & 3) * 4;     // 0,4,8,12
            const float4 av = *reinterpret_cast<const float4*>(&A[(size_t)(m0 + r) * IN_DIM + k0 + kk]);
            As[kk + 0][r] = av.x;
            As[kk + 1][r] = av.y;
            As[kk + 2][r] = av.z;
            As[kk + 3][r] = av.w;
            // stage B tile: 16 k-rows x 64 cols
            const int rr = tid >> 4;          // 0..15
            const int nn = (tid & 15) * 4;    // 0..60
            const float4 bv = *reinterpret_cast<const float4*>(&W[(size_t)(k0 + rr) * G4 + n0 + nn]);
            *reinterpret_cast<float4*>(&Bs[rr][nn]) = bv;
        }
        __syncthreads();
        #pragma unroll
        for (int k = 0; k < 16; ++k) {
            float a[4], b[4];
            *reinterpret_cast<float4*>(a) = *reinterpret_cast<const float4*>(&As[k][tm * 4]);
            *reinterpret_cast<float4*>(b) = *reinterpret_cast<const float4*>(&Bs[k][tn * 4]);
            #pragma unroll
            for (int i = 0; i < 4; ++i)
                #pragma unroll
                for (int j = 0; j < 4; ++j)
                    acc[i][j] += a[i] * b[j];
        }
        __syncthreads();
    }

    #pragma unroll
    for (int i = 0; i < 4; ++i) {
        const int row = m0 + tm * 4 + i;
        const int col = n0 + tn * 4;
        float4 bv = *reinterpret_cast<const float4*>(&bias[col]);
        float4 ov;
        ov.x = acc[i][0] + bv.x;
        ov.y = acc[i][1] + bv.y;
        ov.z = acc[i][2] + bv.z;
        ov.w = acc[i][3] + bv.w;
        *reinterpret_cast<float4*>(&C[(size_t)row * G4 + col]) = ov;
    }
}

// ---------------------------------------------------------------------------
// One LSTM timestep. 64 blocks x 256 threads; thread = (b, hcol) computes all
// 4 gate dot-products (K=512 over h; optionally also K=512 over x if no
// precomputed xW), then the elementwise update.
// ---------------------------------------------------------------------------
__global__ __launch_bounds__(256) void lstm_step(const float* __restrict__ x_t,
                                                 const float* __restrict__ h_prev,
                                                 const float* __restrict__ W,
                                                 const float* __restrict__ bias,
                                                 const float* __restrict__ pre,   // [B, 2048] or null
                                                 const float* __restrict__ c_in,
                                                 float* __restrict__ c_out,
                                                 float* __restrict__ h_out,
                                                 float* __restrict__ hf,
                                                 float* __restrict__ cf,
                                                 int use_pre, int last) {
    const int tid = threadIdx.x;
    const int hc  = tid & 7;
    const int b   = tid >> 3;                  // 0..31
    const int col = blockIdx.x * 8 + hc;       // 0..511

    float a0, a1, a2, a3;
    if (use_pre) {
        const float* p = pre + (size_t)b * G4;
        a0 = p[col];
        a1 = p[col + 512];
        a2 = p[col + 1024];
        a3 = p[col + 1536];
    } else {
        a0 = bias[col];
        a1 = bias[col + 512];
        a2 = bias[col + 1024];
        a3 = bias[col + 1536];
        const float* xr = x_t + (size_t)b * IN_DIM;
        for (int k = 0; k < IN_DIM; k += 4) {
            const float4 xv = *reinterpret_cast<const float4*>(&xr[k]);
            const float xs[4] = {xv.x, xv.y, xv.z, xv.w};
            #pragma unroll
            for (int j = 0; j < 4; ++j) {
                const float* wk = &W[(size_t)(k + j) * G4 + col];
                const float v = xs[j];
                a0 += v * wk[0];
                a1 += v * wk[512];
                a2 += v * wk[1024];
                a3 += v * wk[1536];
            }
        }
    }

    // recurrent part: rows 512..1023 of W
    const float* hr = h_prev + (size_t)b * H_DIM;
    for (int k = 0; k < H_DIM; k += 4) {
        const float4 hv = *reinterpret_cast<const float4*>(&hr[k]);
        const float hs[4] = {hv.x, hv.y, hv.z, hv.w};
        #pragma unroll
        for (int j = 0; j < 4; ++j) {
            const float* wk = &W[(size_t)(512 + k + j) * G4 + col];
            const float v = hs[j];
            a0 += v * wk[0];
            a1 += v * wk[512];
            a2 += v * wk[1024];
            a3 += v * wk[1536];
        }
    }

    const float fg = 1.0f / (1.0f + expf(-a0));
    const float ig = 1.0f / (1.0f + expf(-a1));
    const float gg = tanhf(a2);
    const float og = 1.0f / (1.0f + expf(-a3));

    const float c_old = c_in[(size_t)b * H_DIM + col];
    const float cn = fg * c_old + ig * gg;
    const float hn = og * tanhf(cn);

    c_out[(size_t)b * H_DIM + col] = cn;
    h_out[(size_t)b * H_DIM + col] = hn;
    if (last) {
        hf[(size_t)b * H_DIM + col] = hn;
        cf[(size_t)b * H_DIM + col] = cn;
    }
}

extern "C" void kernel_launch(void* const* d_in, const int* in_sizes, int n_in,
                              void* d_out, int out_size, void* d_ws, size_t ws_size,
                              hipStream_t stream) {
    const float* x    = (const float*)d_in[0];  // [2048, 32, 512]
    const float* h0   = (const float*)d_in[1];  // [1, 32, 512]
    const float* c0   = (const float*)d_in[2];  // [1, 32, 512]
    const float* W    = (const float*)d_in[3];  // [1024, 2048]
    const float* bias = (const float*)d_in[4];  // [2048]

    float* outs = (float*)d_out;                           // [2048, 32, 512]
    float* hf   = outs + (size_t)T_STEPS * BATCH * H_DIM;  // [32, 512]
    float* cf   = hf + BATCH * H_DIM;                      // [32, 512]

    const size_t c_bytes   = (size_t)BATCH * H_DIM * sizeof(float);      // 64 KB
    const size_t pre_bytes = (size_t)T_STEPS * BATCH * G4 * sizeof(float); // 512 MB
    float* c_ws = (float*)d_ws;
    float* pre  = (float*)((char*)d_ws + c_bytes);
    const bool use_pre = ws_size >= pre_bytes + c_bytes;

    if (use_pre) {
        dim3 grid(G4 / 64, (T_STEPS * BATCH) / 64);  // (32, 1024)
        xw_gemm<<<grid, 256, 0, stream>>>(x, W, bias, pre);
    }

    for (int t = 0; t < T_STEPS; ++t) {
        const float* hp = t ? outs + (size_t)(t - 1) * BATCH * H_DIM : h0;
        const float* ci = t ? c_ws : c0;
        lstm_step<<<64, 256, 0, stream>>>(
            x + (size_t)t * BATCH * IN_DIM,
            hp, W, bias,
            use_pre ? pre + (size_t)t * BATCH * G4 : nullptr,
            ci, c_ws,
            outs + (size_t)t * BATCH * H_DIM,
            hf, cf,
            use_pre ? 1 : 0,
            (t == T_STEPS - 1) ? 1 : 0);
    }
}

// Round 2
// 59776.129 us; speedup vs baseline: 1.0557x; 1.0557x over previous
//
#include <hip/hip_runtime.h>
#include <hip/hip_bf16.h>
#include <math.h>

#define T_STEPS 2048
#define BATCH   32
#define IN_DIM  512
#define H_DIM   512
#define G4      2048
#define NWG     64

typedef __attribute__((ext_vector_type(8))) short short8;
typedef __attribute__((ext_vector_type(4))) float f32x4;

__device__ inline unsigned short f2bf(float f) {
    unsigned u = __builtin_bit_cast(unsigned, f);
    unsigned r = (u + 0x7FFFu + ((u >> 16) & 1u)) >> 16;
    return (unsigned short)r;
}
__device__ inline unsigned pack2(float a, float b) {
    return (unsigned)f2bf(a) | ((unsigned)f2bf(b) << 16);
}

// ---------------------------------------------------------------------------
// Transpose W [1024][2048] fp32 -> Wt [2048][1024] bf16  (Wt[n][k] = W[k][n])
// ---------------------------------------------------------------------------
__global__ __launch_bounds__(256) void wt_kernel(const float* __restrict__ W,
                                                 unsigned short* __restrict__ Wt) {
    __shared__ unsigned short tile[32][33];
    const int n0 = blockIdx.x << 5, k0 = blockIdx.y << 5;
    const int tx = threadIdx.x & 31, ty = threadIdx.x >> 5;  // ty 0..7
    #pragma unroll
    for (int r = 0; r < 32; r += 8)
        tile[ty + r][tx] = f2bf(W[(size_t)(k0 + ty + r) * G4 + n0 + tx]);
    __syncthreads();
    #pragma unroll
    for (int r = 0; r < 32; r += 8)
        Wt[(size_t)(n0 + ty + r) * 1024 + k0 + tx] = tile[tx][ty + r];
}

__global__ void init_h(const float* __restrict__ h0, unsigned short* __restrict__ hb) {
    int i = blockIdx.x * 256 + threadIdx.x;   // 16384 total
    hb[i] = f2bf(h0[i]);
}

// ---------------------------------------------------------------------------
// Phase 1: pre[m][col] = x[m][:] @ W[0:512][col] + bias[col], bf16 MFMA.
// M=65536, N=2048, K=512. BM=BN=64, BK=32, 4 waves (wave = mtile).
// ---------------------------------------------------------------------------
__global__ __launch_bounds__(256) void xw_mfma(const float* __restrict__ x,
                                               const unsigned short* __restrict__ Wt,
                                               const float* __restrict__ bias,
                                               float* __restrict__ pre) {
    __shared__ unsigned short As[64][40];   // padded: stride 80B, 16B-aligned rows
    __shared__ unsigned short Bs[64][40];
    const int tid = threadIdx.x;
    const int w = tid >> 6, l = tid & 63;
    const int m0 = blockIdx.y << 6, n0 = blockIdx.x << 6;
    const int srow = tid >> 2, sseg = (tid & 3) << 3;   // staging: row, k-offset (shorts)
    const int arow = (w << 4) + (l & 15);
    const int kb = (l >> 4) << 3;                        // frag k-base (shorts)
    f32x4 acc[4] = {};

    for (int kc = 0; kc < 16; ++kc) {
        const float* xs = x + (size_t)(m0 + srow) * IN_DIM + kc * 32 + sseg;
        float4 xa = *(const float4*)xs;
        float4 xb2 = *(const float4*)(xs + 4);
        int4 av;
        av.x = pack2(xa.x, xa.y);  av.y = pack2(xa.z, xa.w);
        av.z = pack2(xb2.x, xb2.y); av.w = pack2(xb2.z, xb2.w);
        *(int4*)&As[srow][sseg] = av;
        *(int4*)&Bs[srow][sseg] = *(const int4*)(Wt + (size_t)(n0 + srow) * 1024 + kc * 32 + sseg);
        __syncthreads();
        short8 af = *(const short8*)&As[arow][kb];
        #pragma unroll
        for (int n = 0; n < 4; ++n) {
            short8 bf = *(const short8*)&Bs[(n << 4) + (l & 15)][kb];
            acc[n] = __builtin_amdgcn_mfma_f32_16x16x32_bf16(af, bf, acc[n], 0, 0, 0);
        }
        __syncthreads();
    }
    #pragma unroll
    for (int n = 0; n < 4; ++n) {
        const int col = n0 + (n << 4) + (l & 15);
        const float bb = bias[col];
        #pragma unroll
        for (int ri = 0; ri < 4; ++ri) {
            const int row = m0 + (w << 4) + ((l >> 4) << 2) + ri;
            pre[(size_t)row * G4 + col] = acc[n][ri] + bb;
        }
    }
}

// ---------------------------------------------------------------------------
// Persistent scan: 64 WGs x 256 thr. WG g owns hcols [g*8, g*8+8) -> 32 gate
// cols {q*512 + g*8 + j}. W slice LDS-resident (32KB, swizzled); h staged per
// step from double-buffered global bf16; c in registers; 1 grid barrier/step.
// ---------------------------------------------------------------------------
__global__ __launch_bounds__(256, 1) void lstm_scan(
        const unsigned short* __restrict__ Wt,   // [2048][1024], h-part at k+512
        const float* __restrict__ pre,           // [65536][2048]
        const float* __restrict__ c0,            // [32][512]
        unsigned short* __restrict__ hbuf,       // [2][32][512] bf16, hbuf[0] init'd
        float* __restrict__ outs,                // [2048][32][512]
        float* __restrict__ hf, float* __restrict__ cf,
        unsigned int* __restrict__ bar) {
    __shared__ char WlB[32768];   // 32 rows (gatecols) x 512 k bf16, swizzled
    __shared__ char HlB[32768];   // 32 rows (b) x 512 k bf16, swizzled; aliased by Gl
    const int g = blockIdx.x;
    const int tid = threadIdx.x;
    const int w = tid >> 6, l = tid & 63;
    const int b = tid >> 3, j = tid & 7;
    const int hcol = (g << 3) + j;

    // stage W slice once: local row r <-> gatecol (r>>3)*512 + g*8 + (r&7)
    for (int ch = tid; ch < 2048; ch += 256) {
        const int r = ch >> 6, c = ch & 63;
        const int gcol = ((r >> 3) << 9) + (g << 3) + (r & 7);
        int4 v = *(const int4*)(Wt + (size_t)gcol * 1024 + 512 + c * 8);
        *(int4*)(WlB + r * 1024 + ((c * 16) ^ ((r & 7) << 4))) = v;
    }
    float c_val = c0[(b << 9) + hcol];

    const int mt = w & 1, nt = w >> 1;
    const int arow = (mt << 4) + (l & 15);
    const int brow = (nt << 4) + (l & 15);
    const int kb2 = (l >> 4) << 4;                  // frag k byte offset in 64B chunk
    const int aswz = (arow & 7) << 4, bswz = (brow & 7) << 4;
    __syncthreads();

    for (int t = 0; t < T_STEPS; ++t) {
        // prefetch this step's xW+bias values (used after MFMA phase)
        const float* pr = pre + ((size_t)t * BATCH + b) * G4;
        const float p0 = pr[hcol], p1 = pr[hcol + 512], p2 = pr[hcol + 1024], p3 = pr[hcol + 1536];

        // stage h (bf16) into LDS, swizzled
        const unsigned short* hsrc = hbuf + ((t & 1) << 14);
        for (int ch = tid; ch < 2048; ch += 256) {
            const int r = ch >> 6, c = ch & 63;
            int4 v = *(const int4*)(hsrc + (r << 9) + c * 8);
            *(int4*)(HlB + r * 1024 + ((c * 16) ^ ((r & 7) << 4))) = v;
        }
        __syncthreads();

        // h[32,512] @ Wslice[512,32] -> gates[32,32]; wave = (mtile, ntile)
        f32x4 acc = {0.f, 0.f, 0.f, 0.f};
        #pragma unroll
        for (int kc = 0; kc < 16; ++kc) {
            short8 af = *(const short8*)(HlB + arow * 1024 + ((kc * 64 + kb2) ^ aswz));
            short8 bf = *(const short8*)(WlB + brow * 1024 + ((kc * 64 + kb2) ^ bswz));
            acc = __builtin_amdgcn_mfma_f32_16x16x32_bf16(af, bf, acc, 0, 0, 0);
        }
        __syncthreads();                       // all waves done reading HlB
        float* Gl = (float*)HlB;               // alias: gates[32 b][32 gcl]
        #pragma unroll
        for (int ri = 0; ri < 4; ++ri) {
            const int bD = (mt << 4) + ((l >> 4) << 2) + ri;
            const int gcl = (nt << 4) + (l & 15);
            Gl[(bD << 5) + gcl] = acc[ri];
        }
        __syncthreads();

        // elementwise update: thread -> (b, j)
        const float a0 = Gl[(b << 5) + j]      + p0;
        const float a1 = Gl[(b << 5) + 8 + j]  + p1;
        const float a2 = Gl[(b << 5) + 16 + j] + p2;
        const float a3 = Gl[(b << 5) + 24 + j] + p3;
        const float fg = 1.f / (1.f + expf(-a0));
        const float ig = 1.f / (1.f + expf(-a1));
        const float gg = tanhf(a2);
        const float og = 1.f / (1.f + expf(-a3));
        c_val = fg * c_val + ig * gg;
        const float hn = og * tanhf(c_val);

        outs[((size_t)t * BATCH + b) * H_DIM + hcol] = hn;
        hbuf[(((t + 1) & 1) << 14) + (b << 9) + hcol] = f2bf(hn);
        if (t == T_STEPS - 1) {
            hf[(b << 9) + hcol] = hn;
            cf[(b << 9) + hcol] = c_val;
        }

        // grid barrier (device-scope, monotonic counter)
        __threadfence();
        __syncthreads();
        if (tid == 0) {
            __hip_atomic_fetch_add(bar, 1u, __ATOMIC_RELEASE, __HIP_MEMORY_SCOPE_AGENT);
            const unsigned tgt = (unsigned)(t + 1) * NWG;
            while (__hip_atomic_load(bar, __ATOMIC_ACQUIRE, __HIP_MEMORY_SCOPE_AGENT) < tgt)
                __builtin_amdgcn_s_sleep(1);
        }
        __syncthreads();
        __threadfence();
    }
}

// ---------------------------------------------------------------------------
// Fallback path (round-0 kernels) if ws is too small for the fast path.
// ---------------------------------------------------------------------------
__global__ __launch_bounds__(256) void xw_gemm(const float* __restrict__ A,
                                               const float* __restrict__ W,
                                               const float* __restrict__ bias,
                                               float* __restrict__ C) {
    __shared__ float Asf[16][64];
    __shared__ float Bsf[16][64];
    const int bn = blockIdx.x, bm = blockIdx.y;
    const int tid = threadIdx.x;
    const int tm = tid >> 4, tn = tid & 15;
    const int m0 = bm * 64, n0 = bn * 64;
    float acc[4][4] = {};
    for (int k0 = 0; k0 < IN_DIM; k0 += 16) {
        const int r = tid >> 2, kk = (tid & 3) * 4;
        const float4 av = *reinterpret_cast<const float4*>(&A[(size_t)(m0 + r) * IN_DIM + k0 + kk]);
        Asf[kk + 0][r] = av.x; Asf[kk + 1][r] = av.y; Asf[kk + 2][r] = av.z; Asf[kk + 3][r] = av.w;
        const int rr = tid >> 4, nn = (tid & 15) * 4;
        *reinterpret_cast<float4*>(&Bsf[rr][nn]) =
            *reinterpret_cast<const float4*>(&W[(size_t)(k0 + rr) * G4 + n0 + nn]);
        __syncthreads();
        #pragma unroll
        for (int k = 0; k < 16; ++k) {
            float a[4], bq[4];
            *reinterpret_cast<float4*>(a) = *reinterpret_cast<const float4*>(&Asf[k][tm * 4]);
            *reinterpret_cast<float4*>(bq) = *reinterpret_cast<const float4*>(&Bsf[k][tn * 4]);
            #pragma unroll
            for (int i = 0; i < 4; ++i)
                #pragma unroll
                for (int jj = 0; jj < 4; ++jj) acc[i][jj] += a[i] * bq[jj];
        }
        __syncthreads();
    }
    #pragma unroll
    for (int i = 0; i < 4; ++i) {
        const int row = m0 + tm * 4 + i, col = n0 + tn * 4;
        float4 bv = *reinterpret_cast<const float4*>(&bias[col]);
        float4 ov;
        ov.x = acc[i][0] + bv.x; ov.y = acc[i][1] + bv.y;
        ov.z = acc[i][2] + bv.z; ov.w = acc[i][3] + bv.w;
        *reinterpret_cast<float4*>(&C[(size_t)row * G4 + col]) = ov;
    }
}

__global__ __launch_bounds__(256) void lstm_step(const float* __restrict__ h_prev,
                                                 const float* __restrict__ W,
                                                 const float* __restrict__ pre,
                                                 const float* __restrict__ c_in,
                                                 float* __restrict__ c_out,
                                                 float* __restrict__ h_out,
                                                 float* __restrict__ hf,
                                                 float* __restrict__ cf, int last) {
    const int tid = threadIdx.x;
    const int hc = tid & 7, b = tid >> 3;
    const int col = blockIdx.x * 8 + hc;
    const float* p = pre + (size_t)b * G4;
    float a0 = p[col], a1 = p[col + 512], a2 = p[col + 1024], a3 = p[col + 1536];
    const float* hr = h_prev + (size_t)b * H_DIM;
    for (int k = 0; k < H_DIM; k += 4) {
        const float4 hv = *reinterpret_cast<const float4*>(&hr[k]);
        const float hs[4] = {hv.x, hv.y, hv.z, hv.w};
        #pragma unroll
        for (int jj = 0; jj < 4; ++jj) {
            const float* wk = &W[(size_t)(512 + k + jj) * G4 + col];
            const float v = hs[jj];
            a0 += v * wk[0]; a1 += v * wk[512]; a2 += v * wk[1024]; a3 += v * wk[1536];
        }
    }
    const float fg = 1.0f / (1.0f + expf(-a0));
    const float ig = 1.0f / (1.0f + expf(-a1));
    const float gg = tanhf(a2);
    const float og = 1.0f / (1.0f + expf(-a3));
    const float c_old = c_in[(size_t)b * H_DIM + col];
    const float cn = fg * c_old + ig * gg;
    const float hn = og * tanhf(cn);
    c_out[(size_t)b * H_DIM + col] = cn;
    h_out[(size_t)b * H_DIM + col] = hn;
    if (last) { hf[(size_t)b * H_DIM + col] = hn; cf[(size_t)b * H_DIM + col] = cn; }
}

extern "C" void kernel_launch(void* const* d_in, const int* in_sizes, int n_in,
                              void* d_out, int out_size, void* d_ws, size_t ws_size,
                              hipStream_t stream) {
    const float* x    = (const float*)d_in[0];
    const float* h0   = (const float*)d_in[1];
    const float* c0   = (const float*)d_in[2];
    const float* W    = (const float*)d_in[3];
    const float* bias = (const float*)d_in[4];

    float* outs = (float*)d_out;
    float* hf   = outs + (size_t)T_STEPS * BATCH * H_DIM;
    float* cf   = hf + BATCH * H_DIM;

    const size_t OFF_WT  = 536870912ull;            // pre: 512 MB at offset 0
    const size_t OFF_HB  = OFF_WT + 4194304ull;     // Wt: 4 MB
    const size_t OFF_BAR = OFF_HB + 65536ull;       // hbuf: 64 KB
    const size_t NEED    = OFF_BAR + 4096ull;

    if (ws_size >= NEED) {
        float* pre = (float*)d_ws;
        unsigned short* Wt = (unsigned short*)((char*)d_ws + OFF_WT);
        unsigned short* hb = (unsigned short*)((char*)d_ws + OFF_HB);
        unsigned int* bar  = (unsigned int*)((char*)d_ws + OFF_BAR);
        hipMemsetAsync(bar, 0, 64, stream);
        wt_kernel<<<dim3(64, 32), 256, 0, stream>>>(W, Wt);
        init_h<<<64, 256, 0, stream>>>(h0, hb);
        xw_mfma<<<dim3(32, 1024), 256, 0, stream>>>(x, Wt, bias, pre);
        lstm_scan<<<NWG, 256, 0, stream>>>(Wt, pre, c0, hb, outs, hf, cf, bar);
    } else if (ws_size >= 536870912ull + 65536ull) {
        // fp32 fallback: pre at 64KB, c ping-pong at 0
        float* c_ws = (float*)d_ws;
        float* pre  = (float*)((char*)d_ws + 65536);
        dim3 grid(G4 / 64, (T_STEPS * BATCH) / 64);
        xw_gemm<<<grid, 256, 0, stream>>>(x, W, bias, pre);
        for (int t = 0; t < T_STEPS; ++t) {
            const float* hp = t ? outs + (size_t)(t - 1) * BATCH * H_DIM : h0;
            const float* ci = t ? c_ws : c0;
            lstm_step<<<64, 256, 0, stream>>>(hp, W, pre + (size_t)t * BATCH * G4,
                                              ci, c_ws, outs + (size_t)t * BATCH * H_DIM,
                                              hf, cf, (t == T_STEPS - 1) ? 1 : 0);
        }
    }
}

// Round 3
// 15319.141 us; speedup vs baseline: 4.1192x; 3.9021x over previous
//
#include <hip/hip_runtime.h>
#include <math.h>

#define T_STEPS 2048
#define BATCH   32
#define IN_DIM  512
#define H_DIM   512
#define G4      2048
#define NWG     16
#define NTHR    512
#define TC      512      // scan steps per chunk
#define NCHUNK  4
#define GLS     132      // gates LDS row stride (floats), padded

typedef __attribute__((ext_vector_type(8))) short short8;
typedef __attribute__((ext_vector_type(4))) float f32x4;

__device__ inline unsigned short f2bf(float f) {
    unsigned u = __builtin_bit_cast(unsigned, f);
    unsigned r = (u + 0x7FFFu + ((u >> 16) & 1u)) >> 16;
    return (unsigned short)r;
}
__device__ inline unsigned pack2(float a, float b) {
    return (unsigned)f2bf(a) | ((unsigned)f2bf(b) << 16);
}
__device__ inline float sigm(float v) { return 1.f / (1.f + expf(-v)); }

// ---------------------------------------------------------------------------
// Transpose W [1024][2048] fp32 -> Wt [2048][1024] bf16  (Wt[n][k] = W[k][n])
// x-part at k<512, h-part at k>=512.
// ---------------------------------------------------------------------------
__global__ __launch_bounds__(256) void wt_kernel(const float* __restrict__ W,
                                                 unsigned short* __restrict__ Wt) {
    __shared__ unsigned short tile[32][33];
    const int n0 = blockIdx.x << 5, k0 = blockIdx.y << 5;
    const int tx = threadIdx.x & 31, ty = threadIdx.x >> 5;  // ty 0..7
    #pragma unroll
    for (int r = 0; r < 32; r += 8)
        tile[ty + r][tx] = f2bf(W[(size_t)(k0 + ty + r) * G4 + n0 + tx]);
    __syncthreads();
    #pragma unroll
    for (int r = 0; r < 32; r += 8)
        Wt[(size_t)(n0 + ty + r) * 1024 + k0 + tx] = tile[tx][ty + r];
}

__global__ void init_h(const float* __restrict__ h0, unsigned short* __restrict__ hb) {
    int i = blockIdx.x * 256 + threadIdx.x;   // 16384 total
    hb[i] = f2bf(h0[i]);
}

// ---------------------------------------------------------------------------
// Phase 1 (per chunk): pre[m][col] = x[m][:] @ W[0:512][col] + bias[col].
// M=TC*32=16384, N=2048, K=512. BM=BN=64, BK=32, 4 waves (wave = mtile).
// ---------------------------------------------------------------------------
__global__ __launch_bounds__(256) void xw_mfma(const float* __restrict__ x,
                                               const unsigned short* __restrict__ Wt,
                                               const float* __restrict__ bias,
                                               float* __restrict__ pre) {
    __shared__ unsigned short As[64][40];   // row stride 80B (16B-aligned)
    __shared__ unsigned short Bs[64][40];
    const int tid = threadIdx.x;
    const int w = tid >> 6, l = tid & 63;
    const int m0 = blockIdx.y << 6, n0 = blockIdx.x << 6;
    const int srow = tid >> 2, sseg = (tid & 3) << 3;
    const int arow = (w << 4) + (l & 15);
    const int kb = (l >> 4) << 3;
    f32x4 acc[4] = {};

    for (int kc = 0; kc < 16; ++kc) {
        const float* xs = x + (size_t)(m0 + srow) * IN_DIM + kc * 32 + sseg;
        float4 xa = *(const float4*)xs;
        float4 xb2 = *(const float4*)(xs + 4);
        int4 av;
        av.x = pack2(xa.x, xa.y);  av.y = pack2(xa.z, xa.w);
        av.z = pack2(xb2.x, xb2.y); av.w = pack2(xb2.z, xb2.w);
        *(int4*)&As[srow][sseg] = av;
        *(int4*)&Bs[srow][sseg] = *(const int4*)(Wt + (size_t)(n0 + srow) * 1024 + kc * 32 + sseg);
        __syncthreads();
        short8 af = *(const short8*)&As[arow][kb];
        #pragma unroll
        for (int n = 0; n < 4; ++n) {
            short8 bf = *(const short8*)&Bs[(n << 4) + (l & 15)][kb];
            acc[n] = __builtin_amdgcn_mfma_f32_16x16x32_bf16(af, bf, acc[n], 0, 0, 0);
        }
        __syncthreads();
    }
    #pragma unroll
    for (int n = 0; n < 4; ++n) {
        const int col = n0 + (n << 4) + (l & 15);
        const float bb = bias[col];
        #pragma unroll
        for (int ri = 0; ri < 4; ++ri) {
            const int row = m0 + (w << 4) + ((l >> 4) << 2) + ri;
            pre[(size_t)row * G4 + col] = acc[n][ri] + bb;
        }
    }
}

// ---------------------------------------------------------------------------
// Persistent scan (per chunk): 16 WGs x 512 thr (8 waves). WG g owns hidden
// cols [g*32,(g+1)*32) -> 128 gate cols {q*512 + g*32 + j}. W_h slice lives in
// VGPRs (16 B-frags/wave = 64 VGPR); h staged per step into 32KB swizzled LDS;
// c in registers; one grid barrier per step.
// ---------------------------------------------------------------------------
__global__ __launch_bounds__(NTHR, 2) void lstm_scan(
        const unsigned short* __restrict__ Wt,   // [2048][1024], h-part at k+512
        const float* __restrict__ pre,           // chunk: [TC*32][2048]
        const float* __restrict__ cin,           // [32][512] fp32
        float* __restrict__ cout,                // [32][512] fp32
        unsigned short* __restrict__ hbuf,       // [2][32][512] bf16
        float* __restrict__ outs,                // [2048][32][512] (full)
        float* __restrict__ hf, float* __restrict__ cf,
        unsigned int* __restrict__ bar,
        int gt0) {
    __shared__ char Hl[32768];   // h: 32 rows x 512 k bf16, swizzled; aliased by gates
    const int g = blockIdx.x;
    const int tid = threadIdx.x;
    const int w = tid >> 6, l = tid & 63;

    // --- W_h fragments in registers: wave w -> local cols [w*16, w*16+16)
    const int gc = ((w >> 1) << 9) + (g << 5) + ((w & 1) << 4) + (l & 15);
    short8 wf[16];
    #pragma unroll
    for (int kc = 0; kc < 16; ++kc)
        wf[kc] = *(const short8*)(Wt + (size_t)gc * 1024 + 512 + kc * 32 + ((l >> 4) << 3));

    // --- update-phase mapping: thread -> (hc, b2) handling b2 and b2+16
    const int hc = tid & 31;
    const int b2 = tid >> 5;             // 0..15
    const int col = (g << 5) + hc;
    float cv0 = cin[(b2 << 9) + col];
    float cv1 = cin[((b2 + 16) << 9) + col];

    const int arow0 = l & 15, arow1 = (l & 15) + 16;
    const int kbyte = (l >> 4) << 4;
    const int lcw = (w << 4) + (l & 15);

    for (int t = 0; t < TC; ++t) {
        const int gt = gt0 + t;

        // prefetch this step's xW+bias (consumed after MFMA)
        const float* pr0 = pre + ((size_t)t * BATCH + b2) * G4 + col;
        const float* pr1 = pr0 + (16 << 11);
        const float p00 = pr0[0], p01 = pr0[512], p02 = pr0[1024], p03 = pr0[1536];
        const float p10 = pr1[0], p11 = pr1[512], p12 = pr1[1024], p13 = pr1[1536];

        // stage h into LDS (swizzled)
        const unsigned short* hsrc = hbuf + ((gt & 1) << 14);
        #pragma unroll
        for (int s = 0; s < 4; ++s) {
            const int ch = tid + (s << 9);
            const int r = ch >> 6, c = ch & 63;
            int4 v = *(const int4*)(hsrc + (r << 9) + (c << 3));
            *(int4*)(Hl + r * 1024 + ((c << 4) ^ ((r & 7) << 4))) = v;
        }
        __syncthreads();

        // h[32,512] @ Wfrag[512,16] -> gates
        f32x4 acc0 = {0.f, 0.f, 0.f, 0.f}, acc1 = {0.f, 0.f, 0.f, 0.f};
        #pragma unroll
        for (int kc = 0; kc < 16; ++kc) {
            const int kb2 = kc * 64 + kbyte;
            short8 a0 = *(const short8*)(Hl + arow0 * 1024 + (kb2 ^ ((arow0 & 7) << 4)));
            short8 a1 = *(const short8*)(Hl + arow1 * 1024 + (kb2 ^ ((arow1 & 7) << 4)));
            acc0 = __builtin_amdgcn_mfma_f32_16x16x32_bf16(a0, wf[kc], acc0, 0, 0, 0);
            acc1 = __builtin_amdgcn_mfma_f32_16x16x32_bf16(a1, wf[kc], acc1, 0, 0, 0);
        }
        __syncthreads();                 // everyone done reading Hl
        float* Gl = (float*)Hl;          // gates: [32 b][GLS] fp32 (16.9KB)
        #pragma unroll
        for (int ri = 0; ri < 4; ++ri) {
            const int br = ((l >> 4) << 2) + ri;
            Gl[br * GLS + lcw] = acc0[ri];
            Gl[(br + 16) * GLS + lcw] = acc1[ri];
        }
        __syncthreads();

        // elementwise update (2 batch rows per thread)
        const float a00 = Gl[b2 * GLS + hc]      + p00;
        const float a01 = Gl[b2 * GLS + 32 + hc] + p01;
        const float a02 = Gl[b2 * GLS + 64 + hc] + p02;
        const float a03 = Gl[b2 * GLS + 96 + hc] + p03;
        const int b3 = b2 + 16;
        const float a10 = Gl[b3 * GLS + hc]      + p10;
        const float a11 = Gl[b3 * GLS + 32 + hc] + p11;
        const float a12 = Gl[b3 * GLS + 64 + hc] + p12;
        const float a13 = Gl[b3 * GLS + 96 + hc] + p13;

        cv0 = sigm(a00) * cv0 + sigm(a01) * tanhf(a02);
        const float hn0 = sigm(a03) * tanhf(cv0);
        cv1 = sigm(a10) * cv1 + sigm(a11) * tanhf(a12);
        const float hn1 = sigm(a13) * tanhf(cv1);

        float* orow = outs + (size_t)gt * (BATCH * H_DIM);
        orow[(b2 << 9) + col] = hn0;
        orow[(b3 << 9) + col] = hn1;
        unsigned short* hdst = hbuf + (((gt + 1) & 1) << 14);
        hdst[(b2 << 9) + col] = f2bf(hn0);
        hdst[(b3 << 9) + col] = f2bf(hn1);
        if (gt == T_STEPS - 1) {
            hf[(b2 << 9) + col] = hn0;  hf[(b3 << 9) + col] = hn1;
            cf[(b2 << 9) + col] = cv0;  cf[(b3 << 9) + col] = cv1;
        }

        // grid barrier (monotonic counter, device scope)
        __threadfence();
        __syncthreads();
        if (tid == 0) {
            __hip_atomic_fetch_add(bar, 1u, __ATOMIC_RELEASE, __HIP_MEMORY_SCOPE_AGENT);
            const unsigned tgt = (unsigned)(gt + 1) * NWG;
            while (__hip_atomic_load(bar, __ATOMIC_ACQUIRE, __HIP_MEMORY_SCOPE_AGENT) < tgt)
                __builtin_amdgcn_s_sleep(2);
        }
        __syncthreads();
    }

    cout[(b2 << 9) + col] = cv0;
    cout[((b2 + 16) << 9) + col] = cv1;
}

// ---------------------------------------------------------------------------
// Minimal fallback (no big ws): 2048 step launches, fp32, x folded in.
// ---------------------------------------------------------------------------
__global__ __launch_bounds__(256) void lstm_step(const float* __restrict__ x_t,
                                                 const float* __restrict__ h_prev,
                                                 const float* __restrict__ W,
                                                 const float* __restrict__ bias,
                                                 const float* __restrict__ c_in,
                                                 float* __restrict__ c_out,
                                                 float* __restrict__ h_out,
                                                 float* __restrict__ hf,
                                                 float* __restrict__ cf, int last) {
    const int tid = threadIdx.x;
    const int hcc = tid & 7, b = tid >> 3;
    const int col = blockIdx.x * 8 + hcc;
    float a0 = bias[col], a1 = bias[col + 512], a2 = bias[col + 1024], a3 = bias[col + 1536];
    const float* xr = x_t + (size_t)b * IN_DIM;
    const float* hr = h_prev + (size_t)b * H_DIM;
    for (int k = 0; k < IN_DIM; ++k) {
        const float v = xr[k];
        const float* wk = &W[(size_t)k * G4 + col];
        a0 += v * wk[0]; a1 += v * wk[512]; a2 += v * wk[1024]; a3 += v * wk[1536];
    }
    for (int k = 0; k < H_DIM; ++k) {
        const float v = hr[k];
        const float* wk = &W[(size_t)(512 + k) * G4 + col];
        a0 += v * wk[0]; a1 += v * wk[512]; a2 += v * wk[1024]; a3 += v * wk[1536];
    }
    const float cn = sigm(a0) * c_in[(size_t)b * H_DIM + col] + sigm(a1) * tanhf(a2);
    const float hn = sigm(a3) * tanhf(cn);
    c_out[(size_t)b * H_DIM + col] = cn;
    h_out[(size_t)b * H_DIM + col] = hn;
    if (last) { hf[(size_t)b * H_DIM + col] = hn; cf[(size_t)b * H_DIM + col] = cn; }
}

extern "C" void kernel_launch(void* const* d_in, const int* in_sizes, int n_in,
                              void* d_out, int out_size, void* d_ws, size_t ws_size,
                              hipStream_t stream) {
    const float* x    = (const float*)d_in[0];
    const float* h0   = (const float*)d_in[1];
    const float* c0   = (const float*)d_in[2];
    const float* W    = (const float*)d_in[3];
    const float* bias = (const float*)d_in[4];

    float* outs = (float*)d_out;
    float* hf   = outs + (size_t)T_STEPS * BATCH * H_DIM;
    float* cf   = hf + BATCH * H_DIM;

    const size_t OFF_WT  = 134217728ull;             // pre chunk: 128 MB @ 0
    const size_t OFF_HB  = OFF_WT + 4194304ull;      // Wt: 4 MB
    const size_t OFF_C   = OFF_HB + 65536ull;        // hbuf: 64 KB
    const size_t OFF_BAR = OFF_C + 65536ull;         // c: 64 KB
    const size_t NEED    = OFF_BAR + 4096ull;        // ~138.5 MB total

    if (ws_size >= NEED) {
        float* pre = (float*)d_ws;
        unsigned short* Wt = (unsigned short*)((char*)d_ws + OFF_WT);
        unsigned short* hb = (unsigned short*)((char*)d_ws + OFF_HB);
        float* c_ws        = (float*)((char*)d_ws + OFF_C);
        unsigned int* bar  = (unsigned int*)((char*)d_ws + OFF_BAR);

        hipMemsetAsync(bar, 0, 64, stream);
        wt_kernel<<<dim3(64, 32), 256, 0, stream>>>(W, Wt);
        init_h<<<64, 256, 0, stream>>>(h0, hb);
        for (int k = 0; k < NCHUNK; ++k) {
            xw_mfma<<<dim3(32, TC * BATCH / 64), 256, 0, stream>>>(
                x + (size_t)k * TC * BATCH * IN_DIM, Wt, bias, pre);
            lstm_scan<<<NWG, NTHR, 0, stream>>>(
                Wt, pre, (k == 0) ? c0 : c_ws, c_ws, hb, outs, hf, cf, bar, k * TC);
        }
    } else {
        // minimal fallback: c ping-pong in first 64 KB of ws
        float* c_ws = (float*)d_ws;
        for (int t = 0; t < T_STEPS; ++t) {
            const float* hp = t ? outs + (size_t)(t - 1) * BATCH * H_DIM : h0;
            const float* ci = t ? c_ws : c0;
            lstm_step<<<64, 256, 0, stream>>>(x + (size_t)t * BATCH * IN_DIM,
                                              hp, W, bias, ci, c_ws,
                                              outs + (size_t)t * BATCH * H_DIM,
                                              hf, cf, (t == T_STEPS - 1) ? 1 : 0);
        }
    }
}

// Round 4
// 8968.748 us; speedup vs baseline: 7.0359x; 1.7081x over previous
//
#include <hip/hip_runtime.h>
#include <math.h>

#define T_STEPS 2048
#define BATCH   32
#define IN_DIM  512
#define H_DIM   512
#define G4      2048
#define NWG     16
#define NTHR    512
#define TC      512      // scan steps per chunk
#define NCHUNK  4
#define GLS     132      // gates LDS row stride (floats), padded

typedef __attribute__((ext_vector_type(8))) short short8;
typedef __attribute__((ext_vector_type(4))) float f32x4;
typedef __attribute__((ext_vector_type(4))) unsigned u32x4;

__device__ inline unsigned short f2bf(float f) {
    unsigned u = __builtin_bit_cast(unsigned, f);
    unsigned r = (u + 0x7FFFu + ((u >> 16) & 1u)) >> 16;
    return (unsigned short)r;
}
__device__ inline unsigned pack2(float a, float b) {
    return (unsigned)f2bf(a) | ((unsigned)f2bf(b) << 16);
}
__device__ inline float sigm(float v) { return 1.f / (1.f + expf(-v)); }

// ---------------------------------------------------------------------------
// Transpose W [1024][2048] fp32 -> Wt [2048][1024] bf16  (Wt[n][k] = W[k][n])
// ---------------------------------------------------------------------------
__global__ __launch_bounds__(256) void wt_kernel(const float* __restrict__ W,
                                                 unsigned short* __restrict__ Wt) {
    __shared__ unsigned short tile[32][33];
    const int n0 = blockIdx.x << 5, k0 = blockIdx.y << 5;
    const int tx = threadIdx.x & 31, ty = threadIdx.x >> 5;  // ty 0..7
    #pragma unroll
    for (int r = 0; r < 32; r += 8)
        tile[ty + r][tx] = f2bf(W[(size_t)(k0 + ty + r) * G4 + n0 + tx]);
    __syncthreads();
    #pragma unroll
    for (int r = 0; r < 32; r += 8)
        Wt[(size_t)(n0 + ty + r) * 1024 + k0 + tx] = tile[tx][ty + r];
}

__global__ void init_h(const float* __restrict__ h0, unsigned short* __restrict__ hb) {
    int i = blockIdx.x * 256 + threadIdx.x;   // 16384 total
    hb[i] = f2bf(h0[i]);
}

// ---------------------------------------------------------------------------
// Phase 1 (per chunk): pre[m][col] = x[m][:] @ W[0:512][col] + bias[col].
// M=TC*32=16384, N=2048, K=512. BM=BN=64, BK=32, 4 waves (wave = mtile).
// ---------------------------------------------------------------------------
__global__ __launch_bounds__(256) void xw_mfma(const float* __restrict__ x,
                                               const unsigned short* __restrict__ Wt,
                                               const float* __restrict__ bias,
                                               float* __restrict__ pre) {
    __shared__ unsigned short As[64][40];   // row stride 80B (16B-aligned)
    __shared__ unsigned short Bs[64][40];
    const int tid = threadIdx.x;
    const int w = tid >> 6, l = tid & 63;
    const int m0 = blockIdx.y << 6, n0 = blockIdx.x << 6;
    const int srow = tid >> 2, sseg = (tid & 3) << 3;
    const int arow = (w << 4) + (l & 15);
    const int kb = (l >> 4) << 3;
    f32x4 acc[4] = {};

    for (int kc = 0; kc < 16; ++kc) {
        const float* xs = x + (size_t)(m0 + srow) * IN_DIM + kc * 32 + sseg;
        float4 xa = *(const float4*)xs;
        float4 xb2 = *(const float4*)(xs + 4);
        int4 av;
        av.x = pack2(xa.x, xa.y);  av.y = pack2(xa.z, xa.w);
        av.z = pack2(xb2.x, xb2.y); av.w = pack2(xb2.z, xb2.w);
        *(int4*)&As[srow][sseg] = av;
        *(int4*)&Bs[srow][sseg] = *(const int4*)(Wt + (size_t)(n0 + srow) * 1024 + kc * 32 + sseg);
        __syncthreads();
        short8 af = *(const short8*)&As[arow][kb];
        #pragma unroll
        for (int n = 0; n < 4; ++n) {
            short8 bf = *(const short8*)&Bs[(n << 4) + (l & 15)][kb];
            acc[n] = __builtin_amdgcn_mfma_f32_16x16x32_bf16(af, bf, acc[n], 0, 0, 0);
        }
        __syncthreads();
    }
    #pragma unroll
    for (int n = 0; n < 4; ++n) {
        const int col = n0 + (n << 4) + (l & 15);
        const float bb = bias[col];
        #pragma unroll
        for (int ri = 0; ri < 4; ++ri) {
            const int row = m0 + (w << 4) + ((l >> 4) << 2) + ri;
            pre[(size_t)row * G4 + col] = acc[n][ri] + bb;
        }
    }
}

// ---------------------------------------------------------------------------
// Persistent scan (per chunk): 16 WGs x 512 thr (8 waves). WG g owns hidden
// cols [g*32,(g+1)*32) -> 128 gate cols. W_h slice in VGPRs (16 B-frags/wave);
// h exchanged through IC-coherent (sc1) loads/stores — NO L2 flush/inv.
// ---------------------------------------------------------------------------
__global__ __launch_bounds__(NTHR, 2) void lstm_scan(
        const unsigned short* __restrict__ Wt,   // [2048][1024], h-part at k+512
        const float* __restrict__ pre,           // chunk: [TC*32][2048]
        const float* __restrict__ cin,           // [32][512] fp32
        float* __restrict__ cout,                // [32][512] fp32
        unsigned short* __restrict__ hbuf,       // [2][32][512] bf16
        float* __restrict__ outs,                // [2048][32][512] (full)
        float* __restrict__ hf, float* __restrict__ cf,
        unsigned int* __restrict__ bar,
        int gt0) {
    __shared__ char Hl[32768];   // h: 32 rows x 512 k bf16, swizzled; aliased by gates
    const int g = blockIdx.x;
    const int tid = threadIdx.x;
    const int w = tid >> 6, l = tid & 63;

    // --- W_h fragments in registers: wave w -> local gate cols [w*16, w*16+16)
    const int gc = ((w >> 1) << 9) + (g << 5) + ((w & 1) << 4) + (l & 15);
    short8 wf[16];
    #pragma unroll
    for (int kc = 0; kc < 16; ++kc)
        wf[kc] = *(const short8*)(Wt + (size_t)gc * 1024 + 512 + kc * 32 + ((l >> 4) << 3));

    // --- update-phase mapping: thread -> (b, even col pair)
    const int b   = tid >> 4;              // 0..31
    const int hcp = (tid & 15) << 1;       // local col 0,2,..,30
    const int col = (g << 5) + hcp;
    float2 cv = *(const float2*)(cin + (b << 9) + col);

    const int arow0 = l & 15, arow1 = (l & 15) + 16;
    const int kbyte = (l >> 4) << 4;
    const int lcw = (w << 4) + (l & 15);
    const char* HlRd0 = Hl + arow0 * 1024;
    const char* HlRd1 = Hl + arow1 * 1024;
    const int swz0 = (arow0 & 7) << 4, swz1 = (arow1 & 7) << 4;
    __syncthreads();

    for (int t = 0; t < TC; ++t) {
        const int gt = gt0 + t;

        // xW+bias prefetch (plain cached loads; consumed after MFMA)
        const float* pr = pre + ((size_t)t * BATCH + b) * G4 + col;
        const float2 pf = *(const float2*)pr;
        const float2 pi = *(const float2*)(pr + 512);
        const float2 pg = *(const float2*)(pr + 1024);
        const float2 po = *(const float2*)(pr + 1536);

        // stage h: IC-coherent loads (bypass stale L2), swizzled LDS writes.
        // thread -> rows w, w+8, w+16, w+24 (row&7 == w), col chunk l.
        {
            const unsigned short* hsrc = hbuf + ((gt & 1) << 14);
            const unsigned short* hp0 = hsrc + (w << 9) + (l << 3);
            u32x4 v0, v1, v2, v3;
            asm volatile(
                "global_load_dwordx4 %0, %4, off sc1\n\t"
                "global_load_dwordx4 %1, %5, off sc1\n\t"
                "global_load_dwordx4 %2, %6, off sc1\n\t"
                "global_load_dwordx4 %3, %7, off sc1\n\t"
                "s_waitcnt vmcnt(0)"
                : "=&v"(v0), "=&v"(v1), "=&v"(v2), "=&v"(v3)
                : "v"(hp0), "v"(hp0 + 4096), "v"(hp0 + 8192), "v"(hp0 + 12288)
                : "memory");
            char* ld = Hl + w * 1024 + ((l << 4) ^ (w << 4));
            *(u32x4*)(ld)         = v0;
            *(u32x4*)(ld + 8192)  = v1;
            *(u32x4*)(ld + 16384) = v2;
            *(u32x4*)(ld + 24576) = v3;
        }
        __syncthreads();

        // h[32,512] @ Wfrag[512,16] -> gates
        f32x4 acc0 = {0.f, 0.f, 0.f, 0.f}, acc1 = {0.f, 0.f, 0.f, 0.f};
        #pragma unroll
        for (int kc = 0; kc < 16; ++kc) {
            const int kb2 = kc * 64 + kbyte;
            short8 a0 = *(const short8*)(HlRd0 + (kb2 ^ swz0));
            short8 a1 = *(const short8*)(HlRd1 + (kb2 ^ swz1));
            acc0 = __builtin_amdgcn_mfma_f32_16x16x32_bf16(a0, wf[kc], acc0, 0, 0, 0);
            acc1 = __builtin_amdgcn_mfma_f32_16x16x32_bf16(a1, wf[kc], acc1, 0, 0, 0);
        }
        __syncthreads();                 // everyone done reading Hl
        float* Gl = (float*)Hl;          // gates: [32 b][GLS] fp32
        #pragma unroll
        for (int ri = 0; ri < 4; ++ri) {
            const int br = ((l >> 4) << 2) + ri;
            Gl[br * GLS + lcw] = acc0[ri];
            Gl[(br + 16) * GLS + lcw] = acc1[ri];
        }
        __syncthreads();

        // elementwise update: (b, cols hcp, hcp+1)
        const float* grow = Gl + b * GLS + hcp;
        const float f0 = sigm(grow[0]  + pf.x), f1 = sigm(grow[1]  + pf.y);
        const float i0 = sigm(grow[32] + pi.x), i1 = sigm(grow[33] + pi.y);
        const float g0 = tanhf(grow[64] + pg.x), g1 = tanhf(grow[65] + pg.y);
        const float o0 = sigm(grow[96] + po.x), o1 = sigm(grow[97] + po.y);
        cv.x = f0 * cv.x + i0 * g0;
        cv.y = f1 * cv.y + i1 * g1;
        const float hn0 = o0 * tanhf(cv.x);
        const float hn1 = o1 * tanhf(cv.y);

        *(float2*)(outs + (size_t)gt * (BATCH * H_DIM) + (b << 9) + col) =
            make_float2(hn0, hn1);
        // coherent h store for next step (packed 2x bf16, straight to IC)
        {
            unsigned* hdst = (unsigned*)(hbuf + (((gt + 1) & 1) << 14)) + (((b << 9) + col) >> 1);
            const unsigned pk = pack2(hn0, hn1);
            asm volatile("global_store_dword %0, %1, off sc1" :: "v"(hdst), "v"(pk) : "memory");
        }
        if (gt == T_STEPS - 1) {
            *(float2*)(hf + (b << 9) + col) = make_float2(hn0, hn1);
            *(float2*)(cf + (b << 9) + col) = make_float2(cv.x, cv.y);
        }

        // grid barrier: drain h stores to IC, then monotonic counter at IC
        asm volatile("s_waitcnt vmcnt(0)" ::: "memory");
        __syncthreads();
        if (tid == 0) {
            atomicAdd(bar, 1u);
            const unsigned tgt = (unsigned)(gt + 1) * NWG;
            for (;;) {
                unsigned vb;
                asm volatile("global_load_dword %0, %1, off sc1\n\ts_waitcnt vmcnt(0)"
                             : "=v"(vb) : "v"(bar) : "memory");
                if (vb >= tgt) break;
                __builtin_amdgcn_s_sleep(1);
            }
        }
        __syncthreads();
    }

    cout[(b << 9) + col]     = cv.x;
    cout[(b << 9) + col + 1] = cv.y;
}

// ---------------------------------------------------------------------------
// Minimal fallback (no big ws): 2048 step launches, fp32, x folded in.
// ---------------------------------------------------------------------------
__global__ __launch_bounds__(256) void lstm_step(const float* __restrict__ x_t,
                                                 const float* __restrict__ h_prev,
                                                 const float* __restrict__ W,
                                                 const float* __restrict__ bias,
                                                 const float* __restrict__ c_in,
                                                 float* __restrict__ c_out,
                                                 float* __restrict__ h_out,
                                                 float* __restrict__ hf,
                                                 float* __restrict__ cf, int last) {
    const int tid = threadIdx.x;
    const int hcc = tid & 7, b = tid >> 3;
    const int col = blockIdx.x * 8 + hcc;
    float a0 = bias[col], a1 = bias[col + 512], a2 = bias[col + 1024], a3 = bias[col + 1536];
    const float* xr = x_t + (size_t)b * IN_DIM;
    const float* hr = h_prev + (size_t)b * H_DIM;
    for (int k = 0; k < IN_DIM; ++k) {
        const float v = xr[k];
        const float* wk = &W[(size_t)k * G4 + col];
        a0 += v * wk[0]; a1 += v * wk[512]; a2 += v * wk[1024]; a3 += v * wk[1536];
    }
    for (int k = 0; k < H_DIM; ++k) {
        const float v = hr[k];
        const float* wk = &W[(size_t)(512 + k) * G4 + col];
        a0 += v * wk[0]; a1 += v * wk[512]; a2 += v * wk[1024]; a3 += v * wk[1536];
    }
    const float cn = sigm(a0) * c_in[(size_t)b * H_DIM + col] + sigm(a1) * tanhf(a2);
    const float hn = sigm(a3) * tanhf(cn);
    c_out[(size_t)b * H_DIM + col] = cn;
    h_out[(size_t)b * H_DIM + col] = hn;
    if (last) { hf[(size_t)b * H_DIM + col] = hn; cf[(size_t)b * H_DIM + col] = cn; }
}

extern "C" void kernel_launch(void* const* d_in, const int* in_sizes, int n_in,
                              void* d_out, int out_size, void* d_ws, size_t ws_size,
                              hipStream_t stream) {
    const float* x    = (const float*)d_in[0];
    const float* h0   = (const float*)d_in[1];
    const float* c0   = (const float*)d_in[2];
    const float* W    = (const float*)d_in[3];
    const float* bias = (const float*)d_in[4];

    float* outs = (float*)d_out;
    float* hf   = outs + (size_t)T_STEPS * BATCH * H_DIM;
    float* cf   = hf + BATCH * H_DIM;

    const size_t OFF_WT  = 134217728ull;             // pre chunk: 128 MB @ 0
    const size_t OFF_HB  = OFF_WT + 4194304ull;      // Wt: 4 MB
    const size_t OFF_C   = OFF_HB + 65536ull;        // hbuf: 64 KB
    const size_t OFF_BAR = OFF_C + 65536ull;         // c: 64 KB
    const size_t NEED    = OFF_BAR + 4096ull;        // ~138.5 MB total

    if (ws_size >= NEED) {
        float* pre = (float*)d_ws;
        unsigned short* Wt = (unsigned short*)((char*)d_ws + OFF_WT);
        unsigned short* hb = (unsigned short*)((char*)d_ws + OFF_HB);
        float* c_ws        = (float*)((char*)d_ws + OFF_C);
        unsigned int* bar  = (unsigned int*)((char*)d_ws + OFF_BAR);

        hipMemsetAsync(bar, 0, 64, stream);
        wt_kernel<<<dim3(64, 32), 256, 0, stream>>>(W, Wt);
        init_h<<<64, 256, 0, stream>>>(h0, hb);
        for (int k = 0; k < NCHUNK; ++k) {
            xw_mfma<<<dim3(32, TC * BATCH / 64), 256, 0, stream>>>(
                x + (size_t)k * TC * BATCH * IN_DIM, Wt, bias, pre);
            lstm_scan<<<NWG, NTHR, 0, stream>>>(
                Wt, pre, (k == 0) ? c0 : c_ws, c_ws, hb, outs, hf, cf, bar, k * TC);
        }
    } else {
        // minimal fallback: c ping-pong in first 64 KB of ws
        float* c_ws = (float*)d_ws;
        for (int t = 0; t < T_STEPS; ++t) {
            const float* hp = t ? outs + (size_t)(t - 1) * BATCH * H_DIM : h0;
            const float* ci = t ? c_ws : c0;
            lstm_step<<<64, 256, 0, stream>>>(x + (size_t)t * BATCH * IN_DIM,
                                              hp, W, bias, ci, c_ws,
                                              outs + (size_t)t * BATCH * H_DIM,
                                              hf, cf, (t == T_STEPS - 1) ? 1 : 0);
        }
    }
}